// Round 11
// baseline (401.182 us; speedup 1.0000x reference)
//
#include <hip/hip_runtime.h>

// ---------------------------------------------------------------------------
// meta_model: out = (w0*sig(Ll Ll^T) + w1*sig((La La^T)*aa) + w2*sig((Lm Lm^T)*mod)
//                    - sig(Lu Lu^T)) * adj + sig(Lu Lu^T)
// with L* = mlp(feat), w = softmax(ws)
//
// R10: the binding resource was L2/TCC, not HBM. R9 (16-row blocks) moved
// 4.3 GB of fj fragments through L2 (~12 TB/s) because fj had zero reuse
// across waves. Fix is geometric:
//   - block = 8 waves x 16 rows = 128 rows, 16 cols/step, 2048-col strip
//     (128 steps). fj shared block-wide via LDS -> fj L2 traffic /8 (0.5 GB).
//   - fi per wave (its 16 rows, 4g x 4kk = 64 VGPR) pinned via asm loads.
//   - fills: per wave 2 fj + 3 ew global_load_lds into TRIPLE-buffered LDS,
//     issued 1 step ahead (~2600 cyc cover >= 900 HBM latency).
//   - per step: fills(s+1) -> vmcnt(6) [= store(s-1)+5 fills] -> s_barrier
//     -> 19 asm ds_read_b128 (ew XOR-swizzled, fj frag-linear) -> lgkmcnt(0)
//     + sched_barrier -> 16 MFMA -> sigmoid combine -> asm store.
//   - triple buffer kills the fill/read overwrite race across the single
//     per-step barrier (write target = buffer read 2 steps ago).
//   - grid 256 = 1 block/CU; cs=(bid&7)>>1 -> each XCD pair owns one col
//     strip, its 2 MB fj slice L2-resident.
// ---------------------------------------------------------------------------

typedef __attribute__((ext_vector_type(8))) short short8;
typedef __attribute__((ext_vector_type(4))) float f32x4;

__device__ __forceinline__ unsigned short f2bf(float x) {
  union { float f; unsigned u; } v; v.f = x;
  unsigned u = v.u + 0x7FFFu + ((v.u >> 16) & 1u);   // round-to-nearest-even
  return (unsigned short)(u >> 16);
}

__device__ __forceinline__ float sigf(float x) {
  float e = __builtin_amdgcn_exp2f(-1.4426950408889634f * x);
  return __builtin_amdgcn_rcpf(1.0f + e);
}

__device__ __forceinline__ void gload_lds16(const float* g, float* l) {
  __builtin_amdgcn_global_load_lds(
      (const __attribute__((address_space(1))) void*)g,
      (__attribute__((address_space(3))) void*)l, 16, 0, 0);
}
__device__ __forceinline__ void gload_lds16u(const unsigned short* g, unsigned short* l) {
  __builtin_amdgcn_global_load_lds(
      (const __attribute__((address_space(1))) void*)g,
      (__attribute__((address_space(3))) void*)l, 16, 0, 0);
}

__device__ __forceinline__ unsigned lds_off(const void* p) {
  return (unsigned)(uintptr_t)(const __attribute__((address_space(3))) void*)p;
}
__device__ __forceinline__ f32x4 ds_read_f32x4(unsigned a) {
  f32x4 d;
  asm volatile("ds_read_b128 %0, %1" : "=v"(d) : "v"(a));
  return d;
}
__device__ __forceinline__ short8 ds_read_frag(unsigned a) {
  short8 d;
  asm volatile("ds_read_b128 %0, %1" : "=v"(d) : "v"(a));
  return d;
}

// --------------------------- stage A0: feat -> frag -------------------------
__global__ __launch_bounds__(256) void k_featfrag(const float* __restrict__ feat,
                                                  unsigned short* __restrict__ dst) {
  int t = blockIdx.x * 256 + threadIdx.x;   // 8192 rows * 64 chunks
  int row = t >> 6, kc = t & 63;            // 8 cols per thread
  const float4* s = reinterpret_cast<const float4*>(feat + row * 512 + kc * 8);
  float4 v0 = s[0], v1 = s[1];
  short8 o;
  o[0] = f2bf(v0.x); o[1] = f2bf(v0.y); o[2] = f2bf(v0.z); o[3] = f2bf(v0.w);
  o[4] = f2bf(v1.x); o[5] = f2bf(v1.y); o[6] = f2bf(v1.z); o[7] = f2bf(v1.w);
  int mb = row >> 4, kk = kc >> 2;
  int lane = ((kc & 3) << 4) | (row & 15);
  *reinterpret_cast<short8*>(dst + ((size_t)((mb * 16 + kk) * 64 + lane)) * 8) = o;
}

// --------------------- stage A0w: W1/W2 -> B-frag layout ---------------------
__global__ __launch_bounds__(256) void k_wfrag(
    const float* __restrict__ w1_0, const float* __restrict__ w1_1,
    const float* __restrict__ w1_2, const float* __restrict__ w1_3,
    const float* __restrict__ w2_0, const float* __restrict__ w2_1,
    const float* __restrict__ w2_2, const float* __restrict__ w2_3,
    unsigned short* __restrict__ w1f, unsigned short* __restrict__ w2f) {
  int t = blockIdx.x * 256 + threadIdx.x;
  if (t < 32768) {  // W1frag: [g][kk=16][nb=8][lane=64][j=8]
    int lane = t & 63, nb = (t >> 6) & 7, kk = (t >> 9) & 15, g = t >> 13;
    const float* W = g == 0 ? w1_0 : g == 1 ? w1_1 : g == 2 ? w1_2 : w1_3;
    int q = lane >> 4, r = lane & 15;
    int col = nb * 16 + r;
    short8 o;
#pragma unroll
    for (int j = 0; j < 8; ++j) o[j] = f2bf(W[(kk * 32 + q * 8 + j) * 128 + col]);
    *reinterpret_cast<short8*>(w1f + (size_t)t * 8) = o;
  } else if (t < 40960) {  // W2frag: [g][kk=4][nb=8][lane=64][j=8]
    int t2 = t - 32768;
    int lane = t2 & 63, nb = (t2 >> 6) & 7, kk = (t2 >> 9) & 3, g = t2 >> 11;
    const float* W = g == 0 ? w2_0 : g == 1 ? w2_1 : g == 2 ? w2_2 : w2_3;
    int q = lane >> 4, r = lane & 15;
    int col = nb * 16 + r;
    short8 o;
#pragma unroll
    for (int j = 0; j < 8; ++j) o[j] = f2bf(W[(kk * 32 + q * 8 + j) * 128 + col]);
    *reinterpret_cast<short8*>(w2f + (size_t)t2 * 8) = o;
  }
}

// --------------------- stage A1: H = relu(feat@W1cat + b1) -------------------
__global__ __launch_bounds__(256) void k_gemm1(
    const unsigned short* __restrict__ featf, const unsigned short* __restrict__ w1f,
    const float* __restrict__ b1_0, const float* __restrict__ b1_1,
    const float* __restrict__ b1_2, const float* __restrict__ b1_3,
    unsigned short* __restrict__ hfrag) {
  int bi = blockIdx.x, g = blockIdx.y;
  int lane = threadIdx.x & 63, w = threadIdx.x >> 6;
  int wm = w >> 1, wn = w & 1;
  int q = lane >> 4, r = lane & 15;
  int mbase = 8 * bi + 4 * wm;

  f32x4 s[4][4];
#pragma unroll
  for (int mi = 0; mi < 4; ++mi)
#pragma unroll
    for (int nj = 0; nj < 4; ++nj) s[mi][nj] = (f32x4){0.f, 0.f, 0.f, 0.f};

  for (int kk = 0; kk < 16; ++kk) {
    short8 a[4], b[4];
#pragma unroll
    for (int mi = 0; mi < 4; ++mi)
      a[mi] = *reinterpret_cast<const short8*>(
          featf + ((size_t)(((mbase + mi) * 16 + kk) * 64 + lane)) * 8);
#pragma unroll
    for (int nj = 0; nj < 4; ++nj)
      b[nj] = *reinterpret_cast<const short8*>(
          w1f + ((size_t)(((g * 16 + kk) * 8 + 4 * wn + nj) * 64 + lane)) * 8);
#pragma unroll
    for (int mi = 0; mi < 4; ++mi)
#pragma unroll
      for (int nj = 0; nj < 4; ++nj)
        s[mi][nj] = __builtin_amdgcn_mfma_f32_16x16x32_bf16(a[mi], b[nj], s[mi][nj], 0, 0, 0);
  }

  const float* b1 = g == 0 ? b1_0 : g == 1 ? b1_1 : g == 2 ? b1_2 : b1_3;
#pragma unroll
  for (int nj = 0; nj < 4; ++nj) {
    int cl = 64 * wn + 16 * nj + r;
    float bias = b1[cl];
    int Cg = 128 * g + cl;
    int kkd = Cg >> 5;
    int lane2hi = ((Cg >> 3) & 3) << 4;
    int j2 = Cg & 7;
#pragma unroll
    for (int mi = 0; mi < 4; ++mi) {
#pragma unroll
      for (int v = 0; v < 4; ++v) {
        int R = 128 * bi + 64 * wm + 16 * mi + 4 * q + v;
        float val = fmaxf(s[mi][nj][v] + bias, 0.0f);
        int mb = R >> 4;
        int lane2 = lane2hi | (R & 15);
        hfrag[((size_t)((mb * 16 + kkd) * 64 + lane2)) * 8 + j2] = f2bf(val);
      }
    }
  }
}

// --------------------- stage A2: lat_g = H_g@W2_g + b2 -----------------------
__global__ __launch_bounds__(256) void k_gemm2(
    const unsigned short* __restrict__ hfrag, const unsigned short* __restrict__ w2f,
    const float* __restrict__ b2_0, const float* __restrict__ b2_1,
    const float* __restrict__ b2_2, const float* __restrict__ b2_3,
    unsigned short* __restrict__ latf) {
  int bi = blockIdx.x, g = blockIdx.y;
  int lane = threadIdx.x & 63, w = threadIdx.x >> 6;
  int wm = w >> 1, wn = w & 1;
  int q = lane >> 4, r = lane & 15;
  int mbase = 8 * bi + 4 * wm;

  f32x4 s[4][4];
#pragma unroll
  for (int mi = 0; mi < 4; ++mi)
#pragma unroll
    for (int nj = 0; nj < 4; ++nj) s[mi][nj] = (f32x4){0.f, 0.f, 0.f, 0.f};

#pragma unroll
  for (int kk = 0; kk < 4; ++kk) {
    short8 a[4], b[4];
#pragma unroll
    for (int mi = 0; mi < 4; ++mi)
      a[mi] = *reinterpret_cast<const short8*>(
          hfrag + ((size_t)(((mbase + mi) * 16 + 4 * g + kk) * 64 + lane)) * 8);
#pragma unroll
    for (int nj = 0; nj < 4; ++nj)
      b[nj] = *reinterpret_cast<const short8*>(
          w2f + ((size_t)(((g * 4 + kk) * 8 + 4 * wn + nj) * 64 + lane)) * 8);
#pragma unroll
    for (int mi = 0; mi < 4; ++mi)
#pragma unroll
      for (int nj = 0; nj < 4; ++nj)
        s[mi][nj] = __builtin_amdgcn_mfma_f32_16x16x32_bf16(a[mi], b[nj], s[mi][nj], 0, 0, 0);
  }

  const float* b2 = g == 0 ? b2_0 : g == 1 ? b2_1 : g == 2 ? b2_2 : b2_3;
#pragma unroll
  for (int nj = 0; nj < 4; ++nj) {
    int cl = 64 * wn + 16 * nj + r;
    float bias = b2[cl];
    int kkd = cl >> 5;
    int lane2hi = ((cl >> 3) & 3) << 4;
    int j2 = cl & 7;
#pragma unroll
    for (int mi = 0; mi < 4; ++mi) {
#pragma unroll
      for (int v = 0; v < 4; ++v) {
        int R = 128 * bi + 64 * wm + 16 * mi + 4 * q + v;
        float val = s[mi][nj][v] + bias;
        int mb = R >> 4;
        int lane2 = lane2hi | (R & 15);
        latf[((size_t)(((g * 512 + mb) * 4 + kkd) * 64 + lane2)) * 8 + j2] = f2bf(val);
      }
    }
  }
}

// --------------------------- stage B: fused context --------------------------
// Block: 512 thr = 8 waves x 16 rows = 128 rows (brow), sweeping a 2048-col
// strip (cs) in 128 steps of 16 cols. All waves share the step's fj (LDS).
// s = mfma(fj, fi): lane(q,r) reg v -> out(row = 16*mb + r, col = 16*cb + 4q+v).

#define FILD(dst, p, OFF) \
  asm volatile("global_load_dwordx4 %0, %1, off offset:" OFF : "=v"(dst) : "v"(p))

#define GRAMX(G)                                                              \
  {                                                                           \
    short8 _f0 = ds_read_frag(fjc + ((G) * 4 + 0) * 1024u + l16);             \
    short8 _f1 = ds_read_frag(fjc + ((G) * 4 + 1) * 1024u + l16);             \
    short8 _f2 = ds_read_frag(fjc + ((G) * 4 + 2) * 1024u + l16);             \
    short8 _f3 = ds_read_frag(fjc + ((G) * 4 + 3) * 1024u + l16);             \
    asm volatile("s_waitcnt lgkmcnt(0)" ::: "memory");                        \
    __builtin_amdgcn_sched_barrier(0);                                        \
    sg = (f32x4){0.f, 0.f, 0.f, 0.f};                                         \
    sg = __builtin_amdgcn_mfma_f32_16x16x32_bf16(_f0, fi[G][0], sg, 0, 0, 0); \
    sg = __builtin_amdgcn_mfma_f32_16x16x32_bf16(_f1, fi[G][1], sg, 0, 0, 0); \
    sg = __builtin_amdgcn_mfma_f32_16x16x32_bf16(_f2, fi[G][2], sg, 0, 0, 0); \
    sg = __builtin_amdgcn_mfma_f32_16x16x32_bf16(_f3, fi[G][3], sg, 0, 0, 0); \
  }

__global__ __launch_bounds__(512, 2) void k_ctx(
    const unsigned short* __restrict__ latf,
    const float* __restrict__ adj, const float* __restrict__ aa,
    const float* __restrict__ mod, const float* __restrict__ wsv,
    float* __restrict__ out) {
  __shared__ unsigned short fj_lds[3][8192];   // 48 KB: [tbuf][16 frags x 512]
  __shared__ float ew_lds[3][3][2048];         // 72 KB: [tbuf][aa|mod|adj][128r x 16c]

  const int bid = blockIdx.x;                  // 256 blocks = 1/CU
  const int x = bid & 7;                       // XCD under round-robin
  const int cs = x >> 1;                       // col strip 0..3 (2 XCDs each)
  const int brow = ((bid >> 3) << 1) | (x & 1);// 128-row group 0..63
  const int lane = threadIdx.x & 63, w = threadIdx.x >> 6;
  const int q = lane >> 4, r = lane & 15;

  // softmax(ws)
  float s0w = wsv[0], s1w = wsv[1], s2w = wsv[2];
  float mx = fmaxf(fmaxf(s0w, s1w), s2w);
  float e0 = __builtin_amdgcn_exp2f(1.4426950408889634f * (s0w - mx));
  float e1 = __builtin_amdgcn_exp2f(1.4426950408889634f * (s1w - mx));
  float e2 = __builtin_amdgcn_exp2f(1.4426950408889634f * (s2w - mx));
  float inv = __builtin_amdgcn_rcpf(e0 + e1 + e2);
  float w0 = e0 * inv, w1 = e1 * inv, w2 = e2 * inv;

  const size_t GS = (size_t)512 * 2048;        // latf elements per latent
  const int mb = brow * 8 + w;                 // wave's 16-row block 0..511
  const int cb0 = cs * 128;                    // first col-block of strip

  // ---- fi: wave's 16 rows, 4g x 4kk = 16 frags pinned via asm loads ----
  short8 fi[4][4];
  {
    const unsigned short* p0 = latf + ((size_t)(mb * 4) << 9) + (size_t)lane * 8;
    FILD(fi[0][0], p0, "0");    FILD(fi[0][1], p0, "1024");
    FILD(fi[0][2], p0, "2048"); FILD(fi[0][3], p0, "3072");
    p0 += GS;
    FILD(fi[1][0], p0, "0");    FILD(fi[1][1], p0, "1024");
    FILD(fi[1][2], p0, "2048"); FILD(fi[1][3], p0, "3072");
    p0 += GS;
    FILD(fi[2][0], p0, "0");    FILD(fi[2][1], p0, "1024");
    FILD(fi[2][2], p0, "2048"); FILD(fi[2][3], p0, "3072");
    p0 += GS;
    FILD(fi[3][0], p0, "0");    FILD(fi[3][1], p0, "1024");
    FILD(fi[3][2], p0, "2048"); FILD(fi[3][3], p0, "3072");
  }

  // ew fill: wave fills its OWN 16 rows x 16 cols for all 3 mats (1 KB each).
  // lane l: row_local = l>>2, phys 16B-unit pfx = l&3; source col is
  // pre-swizzled (logical = pfx ^ (row&3)) so swizzled ds_reads are bank-even.
  const int rl_f = lane >> 2, pfx_f = lane & 3;
  const size_t ewrow = (size_t)(brow * 128 + w * 16 + rl_f) * 8192
                     + (size_t)cs * 2048 + 4 * (pfx_f ^ (rl_f & 3));
  // fj fill: wave w fills frags f = 2w, 2w+1 (f = g*4+kk) for col-block cb.

  // ---- prologue: fill buffers for s=0 ----
  {
    gload_lds16(aa + ewrow, &ew_lds[0][0][w * 256]);
    gload_lds16(mod + ewrow, &ew_lds[0][1][w * 256]);
    gload_lds16(adj + ewrow, &ew_lds[0][2][w * 256]);
    int f0 = 2 * w, g0 = f0 >> 2, k0 = f0 & 3;
    int f1 = 2 * w + 1, g1 = f1 >> 2, k1 = f1 & 3;
    gload_lds16u(latf + GS * g0 + ((size_t)(cb0 * 4 + k0) << 9) + lane * 8,
                 &fj_lds[0][f0 * 512]);
    gload_lds16u(latf + GS * g1 + ((size_t)(cb0 * 4 + k1) << 9) + lane * 8,
                 &fj_lds[0][f1 * 512]);
  }
  asm volatile("s_waitcnt vmcnt(0)" ::: "memory");
  __builtin_amdgcn_s_barrier();

  const unsigned fjb = lds_off(fj_lds);
  const unsigned ewb = lds_off(ew_lds);
  const unsigned l16 = (unsigned)lane * 16u;
  const unsigned ewlane = (unsigned)(w * 1024 + r * 64 + ((q ^ (r & 3)) << 4));

  int bufR = 0, bufF = 1;

#pragma unroll 1
  for (int s = 0; s < 128; ++s) {
    // ---- fills for s+1 into buf[bufF] ----
    {
      int sF = (s < 127) ? s + 1 : 127;
      size_t ga = ewrow + (size_t)sF * 16;
      gload_lds16(aa + ga, &ew_lds[bufF][0][w * 256]);
      gload_lds16(mod + ga, &ew_lds[bufF][1][w * 256]);
      gload_lds16(adj + ga, &ew_lds[bufF][2][w * 256]);
      int cb = cb0 + sF;
      int f0 = 2 * w, g0 = f0 >> 2, k0 = f0 & 3;
      int f1 = 2 * w + 1, g1 = f1 >> 2, k1 = f1 & 3;
      gload_lds16u(latf + GS * g0 + ((size_t)(cb * 4 + k0) << 9) + lane * 8,
                   &fj_lds[bufF][f0 * 512]);
      gload_lds16u(latf + GS * g1 + ((size_t)(cb * 4 + k1) << 9) + lane * 8,
                   &fj_lds[bufF][f1 * 512]);
    }
    __builtin_amdgcn_sched_barrier(0);
    // retire own fills(s) [older]; keep store(s-1) + fills(s+1) = 6 in flight
    asm volatile("s_waitcnt vmcnt(6)" ::: "memory");
    __builtin_amdgcn_s_barrier();   // everyone's fills(s) are now visible

    const unsigned ewc = ewb + (unsigned)bufR * 24576u + ewlane;
    const unsigned fjc = fjb + (unsigned)bufR * 16384u;

    f32x4 ewa = ds_read_f32x4(ewc);
    f32x4 ewm = ds_read_f32x4(ewc + 8192u);
    f32x4 ewj = ds_read_f32x4(ewc + 16384u);

    f32x4 sg, o4;

    GRAMX(0);   // link
    o4[0] = w0 * sigf(sg[0]); o4[1] = w0 * sigf(sg[1]);
    o4[2] = w0 * sigf(sg[2]); o4[3] = w0 * sigf(sg[3]);

    GRAMX(1);   // aa
    o4[0] += w1 * sigf(sg[0] * ewa[0]); o4[1] += w1 * sigf(sg[1] * ewa[1]);
    o4[2] += w1 * sigf(sg[2] * ewa[2]); o4[3] += w1 * sigf(sg[3] * ewa[3]);

    GRAMX(2);   // mod
    o4[0] += w2 * sigf(sg[0] * ewm[0]); o4[1] += w2 * sigf(sg[1] * ewm[1]);
    o4[2] += w2 * sigf(sg[2] * ewm[2]); o4[3] += w2 * sigf(sg[3] * ewm[3]);

    GRAMX(3);   // unlink + combine
    f32x4 res;
    {
      float u0 = sigf(sg[0]), u1 = sigf(sg[1]), u2 = sigf(sg[2]), u3 = sigf(sg[3]);
      res[0] = ewj[0] * (o4[0] - u0) + u0;
      res[1] = ewj[1] * (o4[1] - u1) + u1;
      res[2] = ewj[2] * (o4[2] - u2) + u2;
      res[3] = ewj[3] * (o4[3] - u3) + u3;
    }
    {
      float* op = out + (size_t)(brow * 128 + w * 16 + r) * 8192
                + (size_t)cs * 2048 + s * 16 + 4 * q;
      asm volatile("global_store_dwordx4 %0, %1, off" ::"v"(op), "v"(res)
                   : "memory");
    }

    bufR = bufF;
    bufF = (bufF == 2) ? 0 : bufF + 1;
  }
}

// ------------------------------------------------------------------------------
extern "C" void kernel_launch(void* const* d_in, const int* in_sizes, int n_in,
                              void* d_out, int out_size, void* d_ws, size_t ws_size,
                              hipStream_t stream) {
  const float* feat = (const float*)d_in[0];
  const float* adj  = (const float*)d_in[1];
  const float* aa   = (const float*)d_in[2];
  const float* mod  = (const float*)d_in[3];
  // g order: 0=link, 1=aa, 2=mod, 3=unlink
  const float* W1g[4] = {(const float*)d_in[4], (const float*)d_in[12],
                         (const float*)d_in[16], (const float*)d_in[8]};
  const float* b1g[4] = {(const float*)d_in[5], (const float*)d_in[13],
                         (const float*)d_in[17], (const float*)d_in[9]};
  const float* W2g[4] = {(const float*)d_in[6], (const float*)d_in[14],
                         (const float*)d_in[18], (const float*)d_in[10]};
  const float* b2g[4] = {(const float*)d_in[7], (const float*)d_in[15],
                         (const float*)d_in[19], (const float*)d_in[11]};
  const float* wsv = (const float*)d_in[20];
  float* out = (float*)d_out;

  // workspace layout (elements of ushort)
  unsigned short* featf = (unsigned short*)d_ws;   // 4,194,304 elems (8 MiB)
  unsigned short* hfrag = featf + 4194304;         // 4,194,304
  unsigned short* latf  = hfrag + 4194304;         // 4,194,304
  unsigned short* w1f   = latf + 4194304;          //   262,144
  unsigned short* w2f   = w1f + 262144;            //    65,536
  if (ws_size < 25821184) return;

  k_featfrag<<<2048, 256, 0, stream>>>(feat, featf);
  k_wfrag<<<160, 256, 0, stream>>>(W1g[0], W1g[1], W1g[2], W1g[3],
                                   W2g[0], W2g[1], W2g[2], W2g[3], w1f, w2f);
  k_gemm1<<<dim3(64, 4), 256, 0, stream>>>(featf, w1f, b1g[0], b1g[1], b1g[2], b1g[3], hfrag);
  k_gemm2<<<dim3(64, 4), 256, 0, stream>>>(hfrag, w2f, b2g[0], b2g[1], b2g[2], b2g[3], latf);
  k_ctx<<<256, 512, 0, stream>>>(latf, adj, aa, mod, wsv, out);
}